// Round 1
// baseline (157.508 us; speedup 1.0000x reference)
//
#include <hip/hip_runtime.h>

// Problem constants
#define BATCH 16384
#define KEYD  64
#define DDIM  128
#define UDIM  128
#define MODES 32

typedef __attribute__((ext_vector_type(8))) short bf16x8;   // 8 bf16 in 4 VGPRs
typedef __attribute__((ext_vector_type(4))) float f32x4;

__device__ __forceinline__ unsigned short f2bf(float f) {
  unsigned u = __float_as_uint(f);
  unsigned r = (u + 0x7FFFu + ((u >> 16) & 1u)) >> 16;  // RNE bf16
  return (unsigned short)r;
}

// ---------------------------------------------------------------------------
// Fused prep (one dispatch) — unchanged from the proven version:
//  blocks [0,512): sim softmax (32 rows/block) + x->bf16.
//  blocks [512,770): cast kernels+biases to bf16 in MFMA-B fragment layout
//    kb16[m][kblk][u][j] = kernels[m][kblk*8+j][u] -> every B-fragment is a
//    contiguous 16B chunk.
// ---------------------------------------------------------------------------
__global__ __launch_bounds__(256) void prep_all(
    const float* __restrict__ key, const float* __restrict__ x,
    const float* __restrict__ sens, const float* __restrict__ keys_map,
    const float* __restrict__ kernels, const float* __restrict__ biases,
    float* __restrict__ sim, unsigned short* __restrict__ x16,
    unsigned short* __restrict__ kb16, unsigned short* __restrict__ bb16) {
  const int t = threadIdx.x;
  const int bid = blockIdx.x;

  if (bid < BATCH / 32) {
    __shared__ float kr[32][KEYD];  // 32 key rows, 8KB
    *(float4*)(&kr[0][0] + t * 4) =
        *(const float4*)(key + (long)bid * 32 * KEYD + t * 4);
    *(float4*)(&kr[0][0] + 1024 + t * 4) =
        *(const float4*)(key + (long)bid * 32 * KEYD + 1024 + t * 4);

    const int lane = t & 63, wave = t >> 6;
    const int m = lane & 31, h = lane >> 5;
    float kreg[32];  // this lane's half of mode m's key row
    {
      const float* kmp = keys_map + m * KEYD + h * 32;
      #pragma unroll
      for (int j = 0; j < 32; j += 4) {
        const float4 v = *(const float4*)(kmp + j);
        kreg[j] = v.x; kreg[j + 1] = v.y; kreg[j + 2] = v.z; kreg[j + 3] = v.w;
      }
    }
    const float sv = sens[m];
    __syncthreads();

    #pragma unroll
    for (int rr = 0; rr < 8; ++rr) {
      const int rl = wave * 8 + rr;
      const long row = (long)bid * 32 + rl;

      float d2h = 0.f;
      #pragma unroll
      for (int j = 0; j < 32; j += 2) {
        const float2 kv = *(const float2*)(&kr[rl][h * 32 + j]);
        float a = kv.x - kreg[j], b = kv.y - kreg[j + 1];
        d2h += a * a + b * b;
      }
      float d2 = d2h + __shfl_xor(d2h, 32, 64);
      float logit = sv / (sqrtf(d2) + 1.0f);
      float mx = logit;
      #pragma unroll
      for (int off = 16; off > 0; off >>= 1) mx = fmaxf(mx, __shfl_xor(mx, off, 64));
      float e = __expf(logit - mx);
      float s = e;
      #pragma unroll
      for (int off = 16; off > 0; off >>= 1) s += __shfl_xor(s, off, 64);
      if (h == 0) sim[row * MODES + m] = e / s;

      const float2 xv = *(const float2*)(x + row * DDIM + lane * 2);
      ushort2 o; o.x = f2bf(xv.x); o.y = f2bf(xv.y);
      *(ushort2*)(x16 + row * DDIM + lane * 2) = o;
    }
  } else {
    int tt = (bid - BATCH / 32) * 256 + t;
    if (tt < MODES * 16 * UDIM) {
      int u = tt & 127, kb = (tt >> 7) & 15, m = tt >> 11;
      const float* src = kernels + (long)((m * 16 + kb) * 8) * UDIM + u;
      ushort4 lo, hi;
      lo.x = f2bf(src[0 * UDIM]); lo.y = f2bf(src[1 * UDIM]);
      lo.z = f2bf(src[2 * UDIM]); lo.w = f2bf(src[3 * UDIM]);
      hi.x = f2bf(src[4 * UDIM]); hi.y = f2bf(src[5 * UDIM]);
      hi.z = f2bf(src[6 * UDIM]); hi.w = f2bf(src[7 * UDIM]);
      *(ushort4*)(kb16 + (long)tt * 8) = lo;
      *(ushort4*)(kb16 + (long)tt * 8 + 4) = hi;
    } else {
      int tb = tt - MODES * 16 * UDIM;
      int u = tb & 127, kb = tb >> 7;
      const float* src = biases + kb * 8 * UDIM + u;
      ushort4 lo, hi;
      lo.x = f2bf(src[0 * UDIM]); lo.y = f2bf(src[1 * UDIM]);
      lo.z = f2bf(src[2 * UDIM]); lo.w = f2bf(src[3 * UDIM]);
      hi.x = f2bf(src[4 * UDIM]); hi.y = f2bf(src[5 * UDIM]);
      hi.z = f2bf(src[6 * UDIM]); hi.w = f2bf(src[7 * UDIM]);
      *(ushort4*)(bb16 + (long)tb * 8) = lo;
      *(ushort4*)(bb16 + (long)tb * 8 + 4) = hi;
    }
  }
}

// ---------------------------------------------------------------------------
// Direct GEMM over all 32 modes in one pass — NO K-split, NO partial buffer,
// NO reduce pass, NO main-loop barriers.
//   grid = (BATCH/64, 2): block = 64 rows x 64 cols (col half ch).
//   4 waves, each wave owns all 64 rows x a 16-col strip (rt=4, ct=1):
//     wave_rows = 64 -> FLOP per B-byte = 64 (above the ~48 break-even),
//     so B fragments go straight from L2 into registers, double-buffered
//     one mode ahead (4 x global_load_dwordx4 hidden under 16 MFMAs).
//   A fragments (x16) live in registers for the whole kernel (64 VGPRs).
//   sim staged once to LDS transposed [mode][row]; per-mode f32x4 broadcast.
//   Bias folded as a K=32 MFMA; output scaled by 1/MODES and stored once.
// ---------------------------------------------------------------------------
#define MODE_STRIDE (16 * UDIM * 8)  // shorts per mode in kb16

#define MODE_STEP(MI, CUR, NXT, PREFETCH)                                       \
  {                                                                             \
    if (PREFETCH) {                                                             \
      _Pragma("unroll")                                                         \
      for (int ks = 0; ks < 4; ++ks)                                            \
        NXT[ks] = *(const bf16x8*)(pM + (long)((MI) + 1) * MODE_STRIDE +        \
                                   ks * (4 * UDIM * 8));                        \
    }                                                                           \
    f32x4 tmp0 = {}, tmp1 = {}, tmp2 = {}, tmp3 = {};                           \
    _Pragma("unroll")                                                           \
    for (int ks = 0; ks < 4; ++ks) {                                            \
      tmp0 = __builtin_amdgcn_mfma_f32_16x16x32_bf16(aF[0][ks], CUR[ks], tmp0, 0, 0, 0); \
      tmp1 = __builtin_amdgcn_mfma_f32_16x16x32_bf16(aF[1][ks], CUR[ks], tmp1, 0, 0, 0); \
      tmp2 = __builtin_amdgcn_mfma_f32_16x16x32_bf16(aF[2][ks], CUR[ks], tmp2, 0, 0, 0); \
      tmp3 = __builtin_amdgcn_mfma_f32_16x16x32_bf16(aF[3][ks], CUR[ks], tmp3, 0, 0, 0); \
    }                                                                           \
    {                                                                           \
      const f32x4 s0 = *(const f32x4*)&simT[MI][0 * 16 + q * 4];                \
      const f32x4 s1 = *(const f32x4*)&simT[MI][1 * 16 + q * 4];                \
      const f32x4 s2 = *(const f32x4*)&simT[MI][2 * 16 + q * 4];                \
      const f32x4 s3 = *(const f32x4*)&simT[MI][3 * 16 + q * 4];                \
      acc[0] += s0 * tmp0; acc[1] += s1 * tmp1;                                 \
      acc[2] += s2 * tmp2; acc[3] += s3 * tmp3;                                 \
    }                                                                           \
  }

__global__ __launch_bounds__(256, 2) void gemm_direct(
    const unsigned short* __restrict__ x16, const unsigned short* __restrict__ kb16,
    const unsigned short* __restrict__ bb16, const float* __restrict__ sim,
    float* __restrict__ out) {
  __shared__ float simT[MODES][64];  // [mode][local row], 8KB

  const int t = threadIdx.x;
  const int lane = t & 63, w = t >> 6;
  const int q = lane >> 4, l16 = lane & 15;
  const long bm = (long)blockIdx.x * 64;
  const int ch = blockIdx.y;                 // column half: cols [ch*64, ch*64+64)
  const int ucol = ch * 64 + w * 16 + l16;   // this lane's output column

  // stage sim transposed: 64 rows x 32 modes (coalesced read, one-time)
  {
    const int r = t >> 2, mg = (t & 3) * 8;
    const float4 v0 = *(const float4*)(sim + (bm + r) * MODES + mg);
    const float4 v1 = *(const float4*)(sim + (bm + r) * MODES + mg + 4);
    simT[mg + 0][r] = v0.x; simT[mg + 1][r] = v0.y;
    simT[mg + 2][r] = v0.z; simT[mg + 3][r] = v0.w;
    simT[mg + 4][r] = v1.x; simT[mg + 5][r] = v1.y;
    simT[mg + 6][r] = v1.z; simT[mg + 7][r] = v1.w;
  }

  // A fragments: full 64-row x K=128 tile in registers (64 VGPRs)
  // A[row = rt*16 + l16][k = ks*32 + q*8 + j]
  bf16x8 aF[4][4];
  #pragma unroll
  for (int rt = 0; rt < 4; ++rt)
    #pragma unroll
    for (int ks = 0; ks < 4; ++ks)
      aF[rt][ks] = *(const bf16x8*)(x16 + (bm + rt * 16 + l16) * DDIM + ks * 32 + q * 8);

  // per-lane base into kb16 (mode 0, ks 0): fragment (ks,q,ucol) is contiguous 16B
  const unsigned short* pM = kb16 + ((long)q * UDIM + ucol) * 8;

  __syncthreads();

  f32x4 acc[4] = {};
  bf16x8 bA[4], bB[4];
  #pragma unroll
  for (int ks = 0; ks < 4; ++ks)
    bA[ks] = *(const bf16x8*)(pM + ks * (4 * UDIM * 8));  // mode 0

  for (int mi = 0; mi < MODES; mi += 2) {
    MODE_STEP(mi, bA, bB, true);                      // compute mode mi, prefetch mi+1
    MODE_STEP(mi + 1, bB, bA, (mi + 2 < MODES));      // compute mode mi+1, prefetch mi+2
  }

  // bias term: one K=32 MFMA (A = sim rows in bf16, B = biases)
  {
    const bf16x8 bb = *(const bf16x8*)(bb16 + ((long)q * UDIM + ucol) * 8);
    #pragma unroll
    for (int rt = 0; rt < 4; ++rt) {
      const float* sp = sim + (bm + rt * 16 + l16) * MODES + q * 8;
      const float4 sv0 = *(const float4*)(sp);
      const float4 sv1 = *(const float4*)(sp + 4);
      bf16x8 sF;
      sF[0] = (short)f2bf(sv0.x); sF[1] = (short)f2bf(sv0.y);
      sF[2] = (short)f2bf(sv0.z); sF[3] = (short)f2bf(sv0.w);
      sF[4] = (short)f2bf(sv1.x); sF[5] = (short)f2bf(sv1.y);
      sF[6] = (short)f2bf(sv1.z); sF[7] = (short)f2bf(sv1.w);
      acc[rt] = __builtin_amdgcn_mfma_f32_16x16x32_bf16(sF, bb, acc[rt], 0, 0, 0);
    }
  }

  // epilogue: direct store, 1/MODES folded in; each out element written once
  #pragma unroll
  for (int rt = 0; rt < 4; ++rt) {
    const long row = bm + rt * 16 + q * 4;
    #pragma unroll
    for (int r = 0; r < 4; ++r)
      out[(row + r) * UDIM + ucol] = acc[rt][r] * (1.0f / MODES);
  }
}

extern "C" void kernel_launch(void* const* d_in, const int* in_sizes, int n_in,
                              void* d_out, int out_size, void* d_ws, size_t ws_size,
                              hipStream_t stream) {
  const float* key      = (const float*)d_in[0];
  const float* x        = (const float*)d_in[1];
  const float* sens     = (const float*)d_in[2];
  const float* keys_map = (const float*)d_in[3];
  const float* kernels  = (const float*)d_in[4];
  const float* biases   = (const float*)d_in[5];
  float* out = (float*)d_out;

  char* ws = (char*)d_ws;
  float*          sim  = (float*)ws;                          // 2 MB
  unsigned short* x16  = (unsigned short*)(ws + (2u << 20));  // 4 MB
  unsigned short* kb16 = (unsigned short*)(ws + (6u << 20));  // 1 MB
  unsigned short* bb16 = (unsigned short*)(ws + (7u << 20));  // 8 KB

  prep_all<<<BATCH / 32 + 258, 256, 0, stream>>>(
      key, x, sens, keys_map, kernels, biases, sim, x16, kb16, bb16);
  gemm_direct<<<dim3(BATCH / 64, 2), 256, 0, stream>>>(x16, kb16, bb16, sim, out);
}

// Round 2
// 114.450 us; speedup vs baseline: 1.3762x; 1.3762x over previous
//
#include <hip/hip_runtime.h>

// Problem constants
#define BATCH 16384
#define KEYD  64
#define DDIM  128
#define UDIM  128
#define MODES 32

typedef __attribute__((ext_vector_type(8))) short bf16x8;   // 8 bf16 in 4 VGPRs
typedef __attribute__((ext_vector_type(4))) float f32x4;

__device__ __forceinline__ unsigned short f2bf(float f) {
  unsigned u = __float_as_uint(f);
  unsigned r = (u + 0x7FFFu + ((u >> 16) & 1u)) >> 16;  // RNE bf16
  return (unsigned short)r;
}

__device__ __forceinline__ void gld_lds16(const void* g, void* l) {
  __builtin_amdgcn_global_load_lds(
      (const __attribute__((address_space(1))) unsigned int*)g,
      (__attribute__((address_space(3))) unsigned int*)l, 16, 0, 0);
}

// ---------------------------------------------------------------------------
// Fused prep (one dispatch) — unchanged proven version:
//  blocks [0,512): sim softmax (32 rows/block) + x->bf16.
//  blocks [512,770): cast kernels+biases to bf16 in MFMA-B fragment layout
//    kb16[m][kblk][u][j] = kernels[m][kblk*8+j][u] -> every B-fragment is a
//    contiguous 16B chunk (global_load_lds width-16 friendly).
// ---------------------------------------------------------------------------
__global__ __launch_bounds__(256) void prep_all(
    const float* __restrict__ key, const float* __restrict__ x,
    const float* __restrict__ sens, const float* __restrict__ keys_map,
    const float* __restrict__ kernels, const float* __restrict__ biases,
    float* __restrict__ sim, unsigned short* __restrict__ x16,
    unsigned short* __restrict__ kb16, unsigned short* __restrict__ bb16) {
  const int t = threadIdx.x;
  const int bid = blockIdx.x;

  if (bid < BATCH / 32) {
    __shared__ float kr[32][KEYD];  // 32 key rows, 8KB
    *(float4*)(&kr[0][0] + t * 4) =
        *(const float4*)(key + (long)bid * 32 * KEYD + t * 4);
    *(float4*)(&kr[0][0] + 1024 + t * 4) =
        *(const float4*)(key + (long)bid * 32 * KEYD + 1024 + t * 4);

    const int lane = t & 63, wave = t >> 6;
    const int m = lane & 31, h = lane >> 5;
    float kreg[32];  // this lane's half of mode m's key row
    {
      const float* kmp = keys_map + m * KEYD + h * 32;
      #pragma unroll
      for (int j = 0; j < 32; j += 4) {
        const float4 v = *(const float4*)(kmp + j);
        kreg[j] = v.x; kreg[j + 1] = v.y; kreg[j + 2] = v.z; kreg[j + 3] = v.w;
      }
    }
    const float sv = sens[m];
    __syncthreads();

    #pragma unroll
    for (int rr = 0; rr < 8; ++rr) {
      const int rl = wave * 8 + rr;
      const long row = (long)bid * 32 + rl;

      float d2h = 0.f;
      #pragma unroll
      for (int j = 0; j < 32; j += 2) {
        const float2 kv = *(const float2*)(&kr[rl][h * 32 + j]);
        float a = kv.x - kreg[j], b = kv.y - kreg[j + 1];
        d2h += a * a + b * b;
      }
      float d2 = d2h + __shfl_xor(d2h, 32, 64);
      float logit = sv / (sqrtf(d2) + 1.0f);
      float mx = logit;
      #pragma unroll
      for (int off = 16; off > 0; off >>= 1) mx = fmaxf(mx, __shfl_xor(mx, off, 64));
      float e = __expf(logit - mx);
      float s = e;
      #pragma unroll
      for (int off = 16; off > 0; off >>= 1) s += __shfl_xor(s, off, 64);
      if (h == 0) sim[row * MODES + m] = e / s;

      const float2 xv = *(const float2*)(x + row * DDIM + lane * 2);
      ushort2 o; o.x = f2bf(xv.x); o.y = f2bf(xv.y);
      *(ushort2*)(x16 + row * DDIM + lane * 2) = o;
    }
  } else {
    int tt = (bid - BATCH / 32) * 256 + t;
    if (tt < MODES * 16 * UDIM) {
      int u = tt & 127, kb = (tt >> 7) & 15, m = tt >> 11;
      const float* src = kernels + (long)((m * 16 + kb) * 8) * UDIM + u;
      ushort4 lo, hi;
      lo.x = f2bf(src[0 * UDIM]); lo.y = f2bf(src[1 * UDIM]);
      lo.z = f2bf(src[2 * UDIM]); lo.w = f2bf(src[3 * UDIM]);
      hi.x = f2bf(src[4 * UDIM]); hi.y = f2bf(src[5 * UDIM]);
      hi.z = f2bf(src[6 * UDIM]); hi.w = f2bf(src[7 * UDIM]);
      *(ushort4*)(kb16 + (long)tt * 8) = lo;
      *(ushort4*)(kb16 + (long)tt * 8 + 4) = hi;
    } else {
      int tb = tt - MODES * 16 * UDIM;
      int u = tb & 127, kb = tb >> 7;
      const float* src = biases + kb * 8 * UDIM + u;
      ushort4 lo, hi;
      lo.x = f2bf(src[0 * UDIM]); lo.y = f2bf(src[1 * UDIM]);
      lo.z = f2bf(src[2 * UDIM]); lo.w = f2bf(src[3 * UDIM]);
      hi.x = f2bf(src[4 * UDIM]); hi.y = f2bf(src[5 * UDIM]);
      hi.z = f2bf(src[6 * UDIM]); hi.w = f2bf(src[7 * UDIM]);
      *(ushort4*)(bb16 + (long)tb * 8) = lo;
      *(ushort4*)(bb16 + (long)tb * 8 + 4) = hi;
    }
  }
}

// ---------------------------------------------------------------------------
// All-modes GEMM, one pass: tile 64 rows x 128 cols, grid 256 (1 block/CU),
// 8 waves (512 threads, 2 waves/SIMD). B staged per mode (32 KB) via async
// global_load_lds into a 2-buffer LDS (proven R0 structure: staging latency
// is absorbed by the fire-and-forget DMA + barrier, tolerant of cold L2).
// NO split-K, NO partial buffer, NO reduce pass. Per-mode loop:
//   sync -> prefetch mode m+1 into other buffer -> ds_read B frags of mode m
//   -> 16 MFMA/wave -> scale by sim and accumulate.
// Bias folded as one K=32 MFMA; out stored once with 1/MODES folded in.
// ---------------------------------------------------------------------------
#define MODE_STRIDE (16 * UDIM * 8)  // shorts per mode in kb16 (32 KB)

__global__ __launch_bounds__(512, 2) void gemm_fused(
    const unsigned short* __restrict__ x16, const unsigned short* __restrict__ kb16,
    const unsigned short* __restrict__ bb16, const float* __restrict__ sim,
    float* __restrict__ out) {
  __shared__ alignas(16) unsigned short bsh[2][MODE_STRIDE];  // 2 x 32KB
  __shared__ float simT[MODES][64];                           // [mode][row], 8KB

  const int t = threadIdx.x;
  const int lane = t & 63, w = t >> 6;
  const int q = lane >> 4, l16 = lane & 15;
  const long bm = (long)blockIdx.x * 64;
  const int ucol = w * 16 + l16;  // this lane's output column (8 waves cover U=128)

  // stage sim transposed: 64 rows x 32 modes, 16B per thread, coalesced
  {
    const int r = t >> 3, mg = (t & 7) * 4;
    const float4 v = *(const float4*)(sim + (bm + r) * MODES + mg);
    simT[mg + 0][r] = v.x; simT[mg + 1][r] = v.y;
    simT[mg + 2][r] = v.z; simT[mg + 3][r] = v.w;
  }

  // A fragments: full 64-row x K=128 tile in registers (64 VGPRs, same in
  // every wave).  A[row = rt*16 + l16][k = ks*32 + q*8 + j]
  bf16x8 aF[4][4];
  #pragma unroll
  for (int rt = 0; rt < 4; ++rt)
    #pragma unroll
    for (int ks = 0; ks < 4; ++ks)
      aF[rt][ks] = *(const bf16x8*)(x16 + (bm + rt * 16 + l16) * DDIM + ks * 32 + q * 8);

  // stage mode 0 into buffer 0: 32 KB = 512 threads x 4 x 16B, linear
  #pragma unroll
  for (int i = 0; i < 4; ++i) {
    const int off = (t + i * 512) * 8;
    gld_lds16(kb16 + off, &bsh[0][off]);
  }

  f32x4 acc[4] = {};

  for (int mi = 0; mi < MODES; ++mi) {
    __syncthreads();  // bsh[mi&1] staged (drains vmcnt); prev-iter reads done
    if (mi < MODES - 1) {  // prefetch next mode into the other buffer
      const unsigned short* src = kb16 + (long)(mi + 1) * MODE_STRIDE;
      unsigned short* dst = bsh[(mi + 1) & 1];
      #pragma unroll
      for (int i = 0; i < 4; ++i) {
        const int off = (t + i * 512) * 8;
        gld_lds16(src + off, dst + off);
      }
    }

    const unsigned short* bs = bsh[mi & 1];
    bf16x8 bF[4];  // [ks], contiguous 16B fragments, conflict-free b128
    #pragma unroll
    for (int ks = 0; ks < 4; ++ks)
      bF[ks] = *(const bf16x8*)&bs[(((ks * 4 + q) * UDIM) + ucol) * 8];

    f32x4 tmp[4] = {};
    #pragma unroll
    for (int ks = 0; ks < 4; ++ks)
      #pragma unroll
      for (int rt = 0; rt < 4; ++rt)
        tmp[rt] = __builtin_amdgcn_mfma_f32_16x16x32_bf16(aF[rt][ks], bF[ks], tmp[rt], 0, 0, 0);

    #pragma unroll
    for (int rt = 0; rt < 4; ++rt) {
      const f32x4 s = *(const f32x4*)&simT[mi][rt * 16 + q * 4];
      acc[rt] += s * tmp[rt];
    }
  }

  // bias term: one K=32 MFMA round (A = sim rows in bf16, B = biases)
  {
    const bf16x8 bb = *(const bf16x8*)(bb16 + ((long)q * UDIM + ucol) * 8);
    #pragma unroll
    for (int rt = 0; rt < 4; ++rt) {
      const float* sp = sim + (bm + rt * 16 + l16) * MODES + q * 8;
      const float4 sv0 = *(const float4*)(sp);
      const float4 sv1 = *(const float4*)(sp + 4);
      bf16x8 sF;
      sF[0] = (short)f2bf(sv0.x); sF[1] = (short)f2bf(sv0.y);
      sF[2] = (short)f2bf(sv0.z); sF[3] = (short)f2bf(sv0.w);
      sF[4] = (short)f2bf(sv1.x); sF[5] = (short)f2bf(sv1.y);
      sF[6] = (short)f2bf(sv1.z); sF[7] = (short)f2bf(sv1.w);
      acc[rt] = __builtin_amdgcn_mfma_f32_16x16x32_bf16(sF, bb, acc[rt], 0, 0, 0);
    }
  }

  // epilogue: direct store, 1/MODES folded in; each out element written once
  #pragma unroll
  for (int rt = 0; rt < 4; ++rt) {
    const long row = bm + rt * 16 + q * 4;
    #pragma unroll
    for (int r = 0; r < 4; ++r)
      out[(row + r) * UDIM + ucol] = acc[rt][r] * (1.0f / MODES);
  }
}

extern "C" void kernel_launch(void* const* d_in, const int* in_sizes, int n_in,
                              void* d_out, int out_size, void* d_ws, size_t ws_size,
                              hipStream_t stream) {
  const float* key      = (const float*)d_in[0];
  const float* x        = (const float*)d_in[1];
  const float* sens     = (const float*)d_in[2];
  const float* keys_map = (const float*)d_in[3];
  const float* kernels  = (const float*)d_in[4];
  const float* biases   = (const float*)d_in[5];
  float* out = (float*)d_out;

  char* ws = (char*)d_ws;
  float*          sim  = (float*)ws;                          // 2 MB
  unsigned short* x16  = (unsigned short*)(ws + (2u << 20));  // 4 MB
  unsigned short* kb16 = (unsigned short*)(ws + (6u << 20));  // 1 MB
  unsigned short* bb16 = (unsigned short*)(ws + (7u << 20));  // 8 KB

  prep_all<<<BATCH / 32 + 258, 256, 0, stream>>>(
      key, x, sens, keys_map, kernels, biases, sim, x16, kb16, bb16);
  gemm_fused<<<dim3(BATCH / 64), 512, 0, stream>>>(x16, kb16, bb16, sim, out);
}

// Round 3
// 107.892 us; speedup vs baseline: 1.4599x; 1.0608x over previous
//
#include <hip/hip_runtime.h>

// Problem constants
#define BATCH 16384
#define KEYD  64
#define DDIM  128
#define UDIM  128
#define MODES 32

typedef __attribute__((ext_vector_type(8))) short bf16x8;   // 8 bf16 in 4 VGPRs
typedef __attribute__((ext_vector_type(4))) float f32x4;

__device__ __forceinline__ unsigned short f2bf(float f) {
  unsigned u = __float_as_uint(f);
  unsigned r = (u + 0x7FFFu + ((u >> 16) & 1u)) >> 16;  // RNE bf16
  return (unsigned short)r;
}

__device__ __forceinline__ void gld_lds16(const void* g, void* l) {
  __builtin_amdgcn_global_load_lds(
      (const __attribute__((address_space(1))) unsigned int*)g,
      (__attribute__((address_space(3))) unsigned int*)l, 16, 0, 0);
}

// ---------------------------------------------------------------------------
// Fused prep (one dispatch) — unchanged proven version:
//  blocks [0,512): sim softmax (32 rows/block) + x->bf16.
//  blocks [512,770): cast kernels+biases to bf16 in MFMA-B fragment layout
//    kb16[m][kblk][u][j] = kernels[m][kblk*8+j][u] -> every B-fragment is a
//    contiguous 16B chunk (global_load_lds width-16 friendly).
// ---------------------------------------------------------------------------
__global__ __launch_bounds__(256) void prep_all(
    const float* __restrict__ key, const float* __restrict__ x,
    const float* __restrict__ sens, const float* __restrict__ keys_map,
    const float* __restrict__ kernels, const float* __restrict__ biases,
    float* __restrict__ sim, unsigned short* __restrict__ x16,
    unsigned short* __restrict__ kb16, unsigned short* __restrict__ bb16) {
  const int t = threadIdx.x;
  const int bid = blockIdx.x;

  if (bid < BATCH / 32) {
    __shared__ float kr[32][KEYD];  // 32 key rows, 8KB
    *(float4*)(&kr[0][0] + t * 4) =
        *(const float4*)(key + (long)bid * 32 * KEYD + t * 4);
    *(float4*)(&kr[0][0] + 1024 + t * 4) =
        *(const float4*)(key + (long)bid * 32 * KEYD + 1024 + t * 4);

    const int lane = t & 63, wave = t >> 6;
    const int m = lane & 31, h = lane >> 5;
    float kreg[32];  // this lane's half of mode m's key row
    {
      const float* kmp = keys_map + m * KEYD + h * 32;
      #pragma unroll
      for (int j = 0; j < 32; j += 4) {
        const float4 v = *(const float4*)(kmp + j);
        kreg[j] = v.x; kreg[j + 1] = v.y; kreg[j + 2] = v.z; kreg[j + 3] = v.w;
      }
    }
    const float sv = sens[m];
    __syncthreads();

    #pragma unroll
    for (int rr = 0; rr < 8; ++rr) {
      const int rl = wave * 8 + rr;
      const long row = (long)bid * 32 + rl;

      float d2h = 0.f;
      #pragma unroll
      for (int j = 0; j < 32; j += 2) {
        const float2 kv = *(const float2*)(&kr[rl][h * 32 + j]);
        float a = kv.x - kreg[j], b = kv.y - kreg[j + 1];
        d2h += a * a + b * b;
      }
      float d2 = d2h + __shfl_xor(d2h, 32, 64);
      float logit = sv / (sqrtf(d2) + 1.0f);
      float mx = logit;
      #pragma unroll
      for (int off = 16; off > 0; off >>= 1) mx = fmaxf(mx, __shfl_xor(mx, off, 64));
      float e = __expf(logit - mx);
      float s = e;
      #pragma unroll
      for (int off = 16; off > 0; off >>= 1) s += __shfl_xor(s, off, 64);
      if (h == 0) sim[row * MODES + m] = e / s;

      const float2 xv = *(const float2*)(x + row * DDIM + lane * 2);
      ushort2 o; o.x = f2bf(xv.x); o.y = f2bf(xv.y);
      *(ushort2*)(x16 + row * DDIM + lane * 2) = o;
    }
  } else {
    int tt = (bid - BATCH / 32) * 256 + t;
    if (tt < MODES * 16 * UDIM) {
      int u = tt & 127, kb = (tt >> 7) & 15, m = tt >> 11;
      const float* src = kernels + (long)((m * 16 + kb) * 8) * UDIM + u;
      ushort4 lo, hi;
      lo.x = f2bf(src[0 * UDIM]); lo.y = f2bf(src[1 * UDIM]);
      lo.z = f2bf(src[2 * UDIM]); lo.w = f2bf(src[3 * UDIM]);
      hi.x = f2bf(src[4 * UDIM]); hi.y = f2bf(src[5 * UDIM]);
      hi.z = f2bf(src[6 * UDIM]); hi.w = f2bf(src[7 * UDIM]);
      *(ushort4*)(kb16 + (long)tt * 8) = lo;
      *(ushort4*)(kb16 + (long)tt * 8 + 4) = hi;
    } else {
      int tb = tt - MODES * 16 * UDIM;
      int u = tb & 127, kb = tb >> 7;
      const float* src = biases + kb * 8 * UDIM + u;
      ushort4 lo, hi;
      lo.x = f2bf(src[0 * UDIM]); lo.y = f2bf(src[1 * UDIM]);
      lo.z = f2bf(src[2 * UDIM]); lo.w = f2bf(src[3 * UDIM]);
      hi.x = f2bf(src[4 * UDIM]); hi.y = f2bf(src[5 * UDIM]);
      hi.z = f2bf(src[6 * UDIM]); hi.w = f2bf(src[7 * UDIM]);
      *(ushort4*)(bb16 + (long)tb * 8) = lo;
      *(ushort4*)(bb16 + (long)tb * 8 + 4) = hi;
    }
  }
}

// ---------------------------------------------------------------------------
// All-modes fused GEMM with restored 2-blocks/CU overlap (the R0 mechanism):
//   grid (BATCH/64, 2) = 512 blocks, 256 threads (4 waves).
//   Block = 64 rows x 64 cols (column half ch = blockIdx.y).
//   Wave  = 64 rows x 16 cols (rt=4, ct=1).
//   LDS: dbuf of 2-mode steps (2 x 32 KB) + simT 8 KB = 72 KB -> exactly
//   2 blocks/CU resident; each per-step barrier drain overlaps the other
//   block's MFMA phase (m114 implicit wave-level overlap).
//   16 barriers total (2 modes/step) instead of 32.
//   Per-mode B-half = 16 contiguous 1KB chunks in kb16; one global_load_lds
//   wave-op per chunk (linear LDS dest, per-lane contiguous global src).
// NO split-K, NO partial buffer, NO reduce pass.
// ---------------------------------------------------------------------------
#define MODE_STRIDE (16 * UDIM * 8)  // shorts per mode in kb16 (32 KB)
#define HALF_STRIDE (16 * 64 * 8)    // shorts per staged mode-half (16 KB)

__global__ __launch_bounds__(256, 2) void gemm_fused(
    const unsigned short* __restrict__ x16, const unsigned short* __restrict__ kb16,
    const unsigned short* __restrict__ bb16, const float* __restrict__ sim,
    float* __restrict__ out) {
  __shared__ alignas(16) unsigned short bsh[2][2 * HALF_STRIDE];  // 2 x 32 KB
  __shared__ float simT[MODES][64];                               // 8 KB

  const int t = threadIdx.x;
  const int lane = t & 63, w = t >> 6;
  const int q = lane >> 4, l16 = lane & 15;
  const long bm = (long)blockIdx.x * 64;
  const int ch = blockIdx.y;      // column half: global cols [ch*64, ch*64+64)
  const int uc = w * 16 + l16;    // local col 0..63 (4 waves cover the half)

  // stage sim transposed: 64 rows x 32 modes; 256 thr x 8 floats, coalesced
  {
    const int r = t >> 2, mg = (t & 3) * 8;
    const float4 v0 = *(const float4*)(sim + (bm + r) * MODES + mg);
    const float4 v1 = *(const float4*)(sim + (bm + r) * MODES + mg + 4);
    simT[mg + 0][r] = v0.x; simT[mg + 1][r] = v0.y;
    simT[mg + 2][r] = v0.z; simT[mg + 3][r] = v0.w;
    simT[mg + 4][r] = v1.x; simT[mg + 5][r] = v1.y;
    simT[mg + 6][r] = v1.z; simT[mg + 7][r] = v1.w;
  }

  // A fragments: full 64-row x K=128 tile in registers (64 VGPRs, same in
  // every wave).  A[row = rt*16 + l16][k = ks*32 + q*8 + j]
  bf16x8 aF[4][4];
  #pragma unroll
  for (int rt = 0; rt < 4; ++rt)
    #pragma unroll
    for (int ks = 0; ks < 4; ++ks)
      aF[rt][ks] = *(const bf16x8*)(x16 + (bm + rt * 16 + l16) * DDIM + ks * 32 + q * 8);

  // stage step 0 (modes 0,1): 32 chunks of 1 KB; chunk c = i*4 + w
  #pragma unroll
  for (int i = 0; i < 8; ++i) {
    const int c = i * 4 + w, ml = c >> 4, kb = c & 15;
    gld_lds16(kb16 + (long)ml * MODE_STRIDE + kb * (UDIM * 8) + ch * (64 * 8) + lane * 8,
              &bsh[0][(c * 64 + lane) * 8]);
  }

  f32x4 acc[4] = {};

  for (int s = 0; s < MODES / 2; ++s) {
    __syncthreads();  // bsh[s&1] staged (drains vmcnt); prev-step reads done
    if (s < MODES / 2 - 1) {  // prefetch next 2-mode step into other buffer
      const unsigned short* srcb = kb16 + (long)(s + 1) * 2 * MODE_STRIDE;
      unsigned short* dst = bsh[(s + 1) & 1];
      #pragma unroll
      for (int i = 0; i < 8; ++i) {
        const int c = i * 4 + w, ml = c >> 4, kb = c & 15;
        gld_lds16(srcb + (long)ml * MODE_STRIDE + kb * (UDIM * 8) + ch * (64 * 8) + lane * 8,
                  dst + (c * 64 + lane) * 8);
      }
    }

    const unsigned short* bs = bsh[s & 1];
    #pragma unroll
    for (int ml = 0; ml < 2; ++ml) {
      const int mi = s * 2 + ml;
      bf16x8 bF[4];  // [ks], contiguous 16B fragments
      #pragma unroll
      for (int ks = 0; ks < 4; ++ks)
        bF[ks] = *(const bf16x8*)&bs[ml * HALF_STRIDE + (((ks * 4 + q) * 64) + uc) * 8];

      f32x4 tmp[4] = {};
      #pragma unroll
      for (int ks = 0; ks < 4; ++ks)
        #pragma unroll
        for (int rt = 0; rt < 4; ++rt)
          tmp[rt] = __builtin_amdgcn_mfma_f32_16x16x32_bf16(aF[rt][ks], bF[ks], tmp[rt], 0, 0, 0);

      #pragma unroll
      for (int rt = 0; rt < 4; ++rt) {
        const f32x4 sv = *(const f32x4*)&simT[mi][rt * 16 + q * 4];
        acc[rt] += sv * tmp[rt];
      }
    }
  }

  // bias term: one K=32 MFMA round (A = sim rows in bf16, B = biases)
  {
    const bf16x8 bb = *(const bf16x8*)(bb16 + ((long)q * UDIM + ch * 64 + uc) * 8);
    #pragma unroll
    for (int rt = 0; rt < 4; ++rt) {
      const float* sp = sim + (bm + rt * 16 + l16) * MODES + q * 8;
      const float4 sv0 = *(const float4*)(sp);
      const float4 sv1 = *(const float4*)(sp + 4);
      bf16x8 sF;
      sF[0] = (short)f2bf(sv0.x); sF[1] = (short)f2bf(sv0.y);
      sF[2] = (short)f2bf(sv0.z); sF[3] = (short)f2bf(sv0.w);
      sF[4] = (short)f2bf(sv1.x); sF[5] = (short)f2bf(sv1.y);
      sF[6] = (short)f2bf(sv1.z); sF[7] = (short)f2bf(sv1.w);
      acc[rt] = __builtin_amdgcn_mfma_f32_16x16x32_bf16(sF, bb, acc[rt], 0, 0, 0);
    }
  }

  // epilogue: direct store, 1/MODES folded in; each out element written once
  #pragma unroll
  for (int rt = 0; rt < 4; ++rt) {
    const long row = bm + rt * 16 + q * 4;
    #pragma unroll
    for (int r = 0; r < 4; ++r)
      out[(row + r) * UDIM + ch * 64 + uc] = acc[rt][r] * (1.0f / MODES);
  }
}

extern "C" void kernel_launch(void* const* d_in, const int* in_sizes, int n_in,
                              void* d_out, int out_size, void* d_ws, size_t ws_size,
                              hipStream_t stream) {
  const float* key      = (const float*)d_in[0];
  const float* x        = (const float*)d_in[1];
  const float* sens     = (const float*)d_in[2];
  const float* keys_map = (const float*)d_in[3];
  const float* kernels  = (const float*)d_in[4];
  const float* biases   = (const float*)d_in[5];
  float* out = (float*)d_out;

  char* ws = (char*)d_ws;
  float*          sim  = (float*)ws;                          // 2 MB
  unsigned short* x16  = (unsigned short*)(ws + (2u << 20));  // 4 MB
  unsigned short* kb16 = (unsigned short*)(ws + (6u << 20));  // 1 MB
  unsigned short* bb16 = (unsigned short*)(ws + (7u << 20));  // 8 KB

  prep_all<<<BATCH / 32 + 258, 256, 0, stream>>>(
      key, x, sens, keys_map, kernels, biases, sim, x16, kb16, bb16);
  gemm_fused<<<dim3(BATCH / 64, 2), 256, 0, stream>>>(x16, kb16, bb16, sim, out);
}